// Round 1
// baseline (1910.905 us; speedup 1.0000x reference)
//
#include <hip/hip_runtime.h>
#include <hip/hip_bf16.h>

#define NN 100000
#define EE 3200000
#define HD 64
#define NF 512
#define NC 256
#define NBLK 98  // ceil(100000/1024)

// ---------------- CSR build ----------------

__global__ __launch_bounds__(256) void count_deg(const int* __restrict__ dst, int* __restrict__ cnt) {
    int e = blockIdx.x * 256 + threadIdx.x;
    if (e < EE) atomicAdd(&cnt[dst[e]], 1);
}

__global__ __launch_bounds__(256) void scan_blocksum(const int* __restrict__ cnt, int* __restrict__ bsum) {
    __shared__ int s[256];
    int t = threadIdx.x, b = blockIdx.x;
    int base = b * 1024 + t * 4;
    int v = 0;
#pragma unroll
    for (int i = 0; i < 4; ++i) {
        int idx = base + i;
        if (idx < NN) v += cnt[idx];
    }
    s[t] = v; __syncthreads();
    for (int d = 128; d > 0; d >>= 1) {
        if (t < d) s[t] += s[t + d];
        __syncthreads();
    }
    if (t == 0) bsum[b] = s[0];
}

__global__ __launch_bounds__(128) void scan_offsets(int* __restrict__ bsum) {
    __shared__ int s[128];
    int t = threadIdx.x;
    int v = (t < NBLK) ? bsum[t] : 0;
    s[t] = v; __syncthreads();
    for (int d = 1; d < 128; d <<= 1) {
        int a = (t >= d) ? s[t - d] : 0;
        __syncthreads();
        s[t] += a;
        __syncthreads();
    }
    if (t < NBLK) bsum[t] = (t == 0) ? 0 : s[t - 1];  // exclusive
}

__global__ __launch_bounds__(256) void scan_write(const int* __restrict__ cnt, const int* __restrict__ bsum,
                                                  int* __restrict__ rowptr) {
    __shared__ int s[256];
    int t = threadIdx.x, b = blockIdx.x;
    int base = b * 1024 + t * 4;
    int v[4]; int tsum = 0;
#pragma unroll
    for (int i = 0; i < 4; ++i) {
        v[i] = (base + i < NN) ? cnt[base + i] : 0;
        tsum += v[i];
    }
    s[t] = tsum; __syncthreads();
    for (int d = 1; d < 256; d <<= 1) {
        int a = (t >= d) ? s[t - d] : 0;
        __syncthreads();
        s[t] += a;
        __syncthreads();
    }
    int off = bsum[b] + (s[t] - tsum);
#pragma unroll
    for (int i = 0; i < 4; ++i) {
        if (base + i < NN) rowptr[base + i] = off;
        off += v[i];
    }
    if (b == NBLK - 1 && t == 255) rowptr[NN] = bsum[b] + s[255];
}

__global__ __launch_bounds__(256) void init_cursor_inv(const int* __restrict__ rowptr, const int* __restrict__ cnt,
                                                       int* __restrict__ cursor, float* __restrict__ inv) {
    int n = blockIdx.x * 256 + threadIdx.x;
    if (n < NN) {
        cursor[n] = rowptr[n];
        int c = cnt[n];
        inv[n] = 1.0f / (float)(c > 1 ? c : 1);
    }
}

__global__ __launch_bounds__(256) void fill_csr(const int* __restrict__ src, const int* __restrict__ dst,
                                                int* __restrict__ cursor, int* __restrict__ csr) {
    int e = blockIdx.x * 256 + threadIdx.x;
    if (e < EE) {
        int d = dst[e];
        int p = atomicAdd(&cursor[d], 1);
        csr[p] = src[e];
    }
}

// ---------------- GEMM: h = x @ Win + b_in  [100000,512]x[512,64] ----------------
// wave per 8 rows, lane = output column. x reads are wave-uniform -> scalar loads.

__global__ __launch_bounds__(256) void gemm_in(const float* __restrict__ x, const float* __restrict__ Win,
                                               const float* __restrict__ b_in, float* __restrict__ h) {
    int lane = threadIdx.x & 63;
    int wave = threadIdx.x >> 6;
    int rowBase = blockIdx.x * 32 + wave * 8;
    int r0 = __builtin_amdgcn_readfirstlane(rowBase);
    float b = b_in[lane];
    float acc[8];
#pragma unroll
    for (int r = 0; r < 8; ++r) acc[r] = b;
    const float* xrow = x + (size_t)r0 * NF;
    for (int k = 0; k < NF; k += 4) {
        float w0 = Win[(k + 0) * HD + lane];
        float w1 = Win[(k + 1) * HD + lane];
        float w2 = Win[(k + 2) * HD + lane];
        float w3 = Win[(k + 3) * HD + lane];
#pragma unroll
        for (int r = 0; r < 8; ++r) {
            float4 xv = *(const float4*)(xrow + (size_t)r * NF + k);
            acc[r] = fmaf(xv.x, w0, acc[r]);
            acc[r] = fmaf(xv.y, w1, acc[r]);
            acc[r] = fmaf(xv.z, w2, acc[r]);
            acc[r] = fmaf(xv.w, w3, acc[r]);
        }
    }
#pragma unroll
    for (int r = 0; r < 8; ++r) h[(size_t)(r0 + r) * HD + lane] = acc[r];
}

// ---------------- Aggregation: agg[n] = mean over in-edges of h[src] ----------------
// one wave per node, lane = feature.

__global__ __launch_bounds__(256) void aggregate(const float* __restrict__ h, const int* __restrict__ rowptr,
                                                 const int* __restrict__ csr, const float* __restrict__ inv,
                                                 float* __restrict__ agg) {
    int lane = threadIdx.x & 63;
    int node = blockIdx.x * 4 + (threadIdx.x >> 6);
    int n = __builtin_amdgcn_readfirstlane(node);
    int start = rowptr[n];
    int end = rowptr[n + 1];
    float acc = 0.f;
    int e = start;
    for (; e + 4 <= end; e += 4) {
        int s0 = csr[e + 0];
        int s1 = csr[e + 1];
        int s2 = csr[e + 2];
        int s3 = csr[e + 3];
        float v0 = h[s0 * HD + lane];
        float v1 = h[s1 * HD + lane];
        float v2 = h[s2 * HD + lane];
        float v3 = h[s3 * HD + lane];
        acc += (v0 + v1) + (v2 + v3);
    }
    for (; e < end; ++e) acc += h[csr[e] * HD + lane];
    agg[n * HD + lane] = acc * inv[n];
}

// ---------------- Layer: h = h + relu(agg@Wl + bl + h@Wr) (in-place, row-local) ----------------

__global__ __launch_bounds__(256) void layer_conv(const float* __restrict__ agg, float* __restrict__ h,
                                                  const float* __restrict__ Wl, const float* __restrict__ Wr,
                                                  const float* __restrict__ bl) {
    int lane = threadIdx.x & 63;
    int wave = threadIdx.x >> 6;
    int rowBase = blockIdx.x * 32 + wave * 8;
    int r0 = __builtin_amdgcn_readfirstlane(rowBase);
    float b = bl[lane];
    float acc[8];
#pragma unroll
    for (int r = 0; r < 8; ++r) acc[r] = b;
    for (int k = 0; k < HD; k += 4) {
        float wl0 = Wl[(k + 0) * HD + lane];
        float wl1 = Wl[(k + 1) * HD + lane];
        float wl2 = Wl[(k + 2) * HD + lane];
        float wl3 = Wl[(k + 3) * HD + lane];
        float wr0 = Wr[(k + 0) * HD + lane];
        float wr1 = Wr[(k + 1) * HD + lane];
        float wr2 = Wr[(k + 2) * HD + lane];
        float wr3 = Wr[(k + 3) * HD + lane];
#pragma unroll
        for (int r = 0; r < 8; ++r) {
            float4 av = *(const float4*)(agg + (size_t)(r0 + r) * HD + k);
            float4 hv = *(const float4*)(h + (size_t)(r0 + r) * HD + k);
            acc[r] = fmaf(av.x, wl0, acc[r]);
            acc[r] = fmaf(av.y, wl1, acc[r]);
            acc[r] = fmaf(av.z, wl2, acc[r]);
            acc[r] = fmaf(av.w, wl3, acc[r]);
            acc[r] = fmaf(hv.x, wr0, acc[r]);
            acc[r] = fmaf(hv.y, wr1, acc[r]);
            acc[r] = fmaf(hv.z, wr2, acc[r]);
            acc[r] = fmaf(hv.w, wr3, acc[r]);
        }
    }
#pragma unroll
    for (int r = 0; r < 8; ++r) {
        size_t idx = (size_t)(r0 + r) * HD + lane;
        float hold = h[idx];
        float c = acc[r];
        h[idx] = hold + (c > 0.f ? c : 0.f);
    }
}

// ---------------- Output GEMM: out = h @ Wout + b_out  [100000,64]x[64,256] ----------------

__global__ __launch_bounds__(256) void gemm_out_k(const float* __restrict__ h, const float* __restrict__ Wout,
                                                  const float* __restrict__ b_out, float* __restrict__ out) {
    int j = threadIdx.x;  // 0..255 output column
    int r0 = __builtin_amdgcn_readfirstlane((int)(blockIdx.x * 8));
    float b = b_out[j];
    float acc[8];
#pragma unroll
    for (int r = 0; r < 8; ++r) acc[r] = b;
    for (int k = 0; k < HD; k += 4) {
        float w0 = Wout[(k + 0) * NC + j];
        float w1 = Wout[(k + 1) * NC + j];
        float w2 = Wout[(k + 2) * NC + j];
        float w3 = Wout[(k + 3) * NC + j];
#pragma unroll
        for (int r = 0; r < 8; ++r) {
            float4 hv = *(const float4*)(h + (size_t)(r0 + r) * HD + k);
            acc[r] = fmaf(hv.x, w0, acc[r]);
            acc[r] = fmaf(hv.y, w1, acc[r]);
            acc[r] = fmaf(hv.z, w2, acc[r]);
            acc[r] = fmaf(hv.w, w3, acc[r]);
        }
    }
#pragma unroll
    for (int r = 0; r < 8; ++r) out[(size_t)(r0 + r) * NC + j] = acc[r];
}

extern "C" void kernel_launch(void* const* d_in, const int* in_sizes, int n_in,
                              void* d_out, int out_size, void* d_ws, size_t ws_size,
                              hipStream_t stream) {
    const float* x    = (const float*)d_in[0];
    const int*   ei   = (const int*)d_in[1];   // [2, E]: src then dst
    const float* Win  = (const float*)d_in[2];
    const float* b_in = (const float*)d_in[3];
    const float* Wl   = (const float*)d_in[4]; // [4,64,64]
    const float* bl   = (const float*)d_in[5]; // [4,64]
    const float* Wr   = (const float*)d_in[6]; // [4,64,64]
    const float* Wout = (const float*)d_in[7];
    const float* b_out= (const float*)d_in[8];
    float* out = (float*)d_out;

    const int* src = ei;
    const int* dst = ei + EE;

    // workspace layout (16B-aligned chunks)
    char* ws = (char*)d_ws;
    float* h      = (float*)ws;                       // 6.4M floats
    float* agg    = h + (size_t)NN * HD;              // 6.4M floats
    int*   cnt    = (int*)(agg + (size_t)NN * HD);    // 100000
    int*   rowptr = cnt + NN;                         // 100001 (pad to 100004)
    int*   cursor = rowptr + 100004;                  // 100000
    int*   bsum   = cursor + NN;                      // 128
    int*   csr    = bsum + 128;                       // 3.2M
    float* inv    = (float*)(csr + EE);               // 100000

    hipMemsetAsync(cnt, 0, NN * sizeof(int), stream);

    count_deg<<<EE / 256, 256, 0, stream>>>(dst, cnt);
    scan_blocksum<<<NBLK, 256, 0, stream>>>(cnt, bsum);
    scan_offsets<<<1, 128, 0, stream>>>(bsum);
    scan_write<<<NBLK, 256, 0, stream>>>(cnt, bsum, rowptr);
    init_cursor_inv<<<(NN + 255) / 256, 256, 0, stream>>>(rowptr, cnt, cursor, inv);
    fill_csr<<<EE / 256, 256, 0, stream>>>(src, dst, cursor, csr);

    gemm_in<<<NN / 32, 256, 0, stream>>>(x, Win, b_in, h);

    for (int i = 0; i < 4; ++i) {
        aggregate<<<NN / 4, 256, 0, stream>>>(h, rowptr, csr, inv, agg);
        layer_conv<<<NN / 32, 256, 0, stream>>>(agg, h, Wl + (size_t)i * HD * HD,
                                                Wr + (size_t)i * HD * HD, bl + (size_t)i * HD);
    }

    gemm_out_k<<<NN / 8, 256, 0, stream>>>(h, Wout, b_out, out);
}

// Round 2
// 1501.699 us; speedup vs baseline: 1.2725x; 1.2725x over previous
//
#include <hip/hip_runtime.h>
#include <hip/hip_bf16.h>

#define NN 100000
#define EE 3200000
#define HD 64
#define NF 512
#define NC 256
#define NBLK 98  // ceil(100000/1024)

// ---------------- CSR build ----------------

__global__ __launch_bounds__(256) void count_deg(const int* __restrict__ dst, int* __restrict__ cnt) {
    int e = blockIdx.x * 256 + threadIdx.x;
    if (e < EE) atomicAdd(&cnt[dst[e]], 1);
}

__global__ __launch_bounds__(256) void scan_blocksum(const int* __restrict__ cnt, int* __restrict__ bsum) {
    __shared__ int s[256];
    int t = threadIdx.x, b = blockIdx.x;
    int base = b * 1024 + t * 4;
    int v = 0;
#pragma unroll
    for (int i = 0; i < 4; ++i) {
        int idx = base + i;
        if (idx < NN) v += cnt[idx];
    }
    s[t] = v; __syncthreads();
    for (int d = 128; d > 0; d >>= 1) {
        if (t < d) s[t] += s[t + d];
        __syncthreads();
    }
    if (t == 0) bsum[b] = s[0];
}

__global__ __launch_bounds__(128) void scan_offsets(int* __restrict__ bsum) {
    __shared__ int s[128];
    int t = threadIdx.x;
    int v = (t < NBLK) ? bsum[t] : 0;
    s[t] = v; __syncthreads();
    for (int d = 1; d < 128; d <<= 1) {
        int a = (t >= d) ? s[t - d] : 0;
        __syncthreads();
        s[t] += a;
        __syncthreads();
    }
    if (t < NBLK) bsum[t] = (t == 0) ? 0 : s[t - 1];  // exclusive
}

__global__ __launch_bounds__(256) void scan_write(const int* __restrict__ cnt, const int* __restrict__ bsum,
                                                  int* __restrict__ rowptr) {
    __shared__ int s[256];
    int t = threadIdx.x, b = blockIdx.x;
    int base = b * 1024 + t * 4;
    int v[4]; int tsum = 0;
#pragma unroll
    for (int i = 0; i < 4; ++i) {
        v[i] = (base + i < NN) ? cnt[base + i] : 0;
        tsum += v[i];
    }
    s[t] = tsum; __syncthreads();
    for (int d = 1; d < 256; d <<= 1) {
        int a = (t >= d) ? s[t - d] : 0;
        __syncthreads();
        s[t] += a;
        __syncthreads();
    }
    int off = bsum[b] + (s[t] - tsum);
#pragma unroll
    for (int i = 0; i < 4; ++i) {
        if (base + i < NN) rowptr[base + i] = off;
        off += v[i];
    }
    if (b == NBLK - 1 && t == 255) rowptr[NN] = bsum[b] + s[255];
}

__global__ __launch_bounds__(256) void init_cursor_inv(const int* __restrict__ rowptr, const int* __restrict__ cnt,
                                                       int* __restrict__ cursor, float* __restrict__ inv) {
    int n = blockIdx.x * 256 + threadIdx.x;
    if (n < NN) {
        cursor[n] = rowptr[n];
        int c = cnt[n];
        inv[n] = 1.0f / (float)(c > 1 ? c : 1);
    }
}

__global__ __launch_bounds__(256) void fill_csr(const int* __restrict__ src, const int* __restrict__ dst,
                                                int* __restrict__ cursor, int* __restrict__ csr) {
    int e = blockIdx.x * 256 + threadIdx.x;
    if (e < EE) {
        int d = dst[e];
        int p = atomicAdd(&cursor[d], 1);
        csr[p] = src[e];
    }
}

// ---------------- GEMM: h = x @ Win + b_in  [100000,512]x[512,64] ----------------
// 64 rows per block, LDS-staged x tile, wave w owns rows 16w..16w+15, lane = col.

__global__ __launch_bounds__(256) void gemm_in(const float* __restrict__ x, const float* __restrict__ Win,
                                               const float* __restrict__ b_in, float* __restrict__ h) {
    __shared__ float xs[64 * 64];  // 16 KB
    int tid = threadIdx.x;
    int lane = tid & 63, wave = tid >> 6;
    int rowBase = blockIdx.x * 64;
    float bb = b_in[lane];
    float acc[16];
#pragma unroll
    for (int r = 0; r < 16; ++r) acc[r] = bb;

    for (int kt = 0; kt < NF; kt += 64) {
        __syncthreads();  // previous tile fully consumed
#pragma unroll
        for (int i = 0; i < 4; ++i) {
            int idx = tid + 256 * i;     // 0..1023
            int r = idx >> 4;            // tile row
            int c4 = idx & 15;           // float4 within row
            int grow = rowBase + r;
            if (grow >= NN) grow = NN - 1;
            float4 v = *(const float4*)(x + (size_t)grow * NF + kt + c4 * 4);
            *(float4*)(xs + r * 64 + c4 * 4) = v;
        }
        __syncthreads();
        const float* wsrc = Win + (size_t)kt * HD;
        for (int k = 0; k < 64; k += 4) {
            float w0 = wsrc[(k + 0) * HD + lane];
            float w1 = wsrc[(k + 1) * HD + lane];
            float w2 = wsrc[(k + 2) * HD + lane];
            float w3 = wsrc[(k + 3) * HD + lane];
#pragma unroll
            for (int r = 0; r < 16; ++r) {
                float4 xv = *(const float4*)(xs + (wave * 16 + r) * 64 + k);
                acc[r] = fmaf(xv.x, w0, acc[r]);
                acc[r] = fmaf(xv.y, w1, acc[r]);
                acc[r] = fmaf(xv.z, w2, acc[r]);
                acc[r] = fmaf(xv.w, w3, acc[r]);
            }
        }
    }
#pragma unroll
    for (int r = 0; r < 16; ++r) {
        int row = rowBase + wave * 16 + r;
        if (row < NN) h[(size_t)row * HD + lane] = acc[r];
    }
}

// ---------------- Aggregation: agg[n] = mean over in-edges of h[src] ----------------
// one wave per node; lane = (edge slot q = lane>>4, feature quad f = lane&15).
// each lane loads a float4 -> one instruction gathers 4 edge rows (1024 B).

__global__ __launch_bounds__(256) void aggregate(const float4* __restrict__ h4, const int* __restrict__ rowptr,
                                                 const int* __restrict__ csr, const float* __restrict__ inv,
                                                 float4* __restrict__ agg4) {
    int tid = threadIdx.x;
    int lane = tid & 63;
    int q = lane >> 4;
    int f = lane & 15;
    int node = blockIdx.x * 4 + (tid >> 6);
    int n = __builtin_amdgcn_readfirstlane(node);
    int start = rowptr[n];
    int end = rowptr[n + 1];

    float4 acc0 = make_float4(0.f, 0.f, 0.f, 0.f);
    float4 acc1 = make_float4(0.f, 0.f, 0.f, 0.f);
    int e = start;
    int end8 = start + ((end - start) & ~7);
    for (; e < end8; e += 8) {
        int s0 = csr[e + q];
        int s1 = csr[e + 4 + q];
        float4 v0 = h4[(size_t)s0 * 16 + f];
        float4 v1 = h4[(size_t)s1 * 16 + f];
        acc0.x += v0.x; acc0.y += v0.y; acc0.z += v0.z; acc0.w += v0.w;
        acc1.x += v1.x; acc1.y += v1.y; acc1.z += v1.z; acc1.w += v1.w;
    }
    if (e + q < end) {
        int s = csr[e + q];
        float4 v = h4[(size_t)s * 16 + f];
        acc0.x += v.x; acc0.y += v.y; acc0.z += v.z; acc0.w += v.w;
    }
    e += 4;
    if (e + q < end) {
        int s = csr[e + q];
        float4 v = h4[(size_t)s * 16 + f];
        acc1.x += v.x; acc1.y += v.y; acc1.z += v.z; acc1.w += v.w;
    }

    float4 a;
    a.x = acc0.x + acc1.x;
    a.y = acc0.y + acc1.y;
    a.z = acc0.z + acc1.z;
    a.w = acc0.w + acc1.w;
    a.x += __shfl_xor(a.x, 16); a.x += __shfl_xor(a.x, 32);
    a.y += __shfl_xor(a.y, 16); a.y += __shfl_xor(a.y, 32);
    a.z += __shfl_xor(a.z, 16); a.z += __shfl_xor(a.z, 32);
    a.w += __shfl_xor(a.w, 16); a.w += __shfl_xor(a.w, 32);

    if (q == 0) {
        float s = inv[n];
        float4 r;
        r.x = a.x * s; r.y = a.y * s; r.z = a.z * s; r.w = a.w * s;
        agg4[(size_t)n * 16 + f] = r;
    }
}

// ---------------- Layer: h = h + relu(agg@Wl + bl + h@Wr) (in-place, row-local) ----------------
// 64 rows per block, LDS-staged agg & h tiles.

__global__ __launch_bounds__(256) void layer_conv(const float* __restrict__ agg, float* __restrict__ h,
                                                  const float* __restrict__ Wl, const float* __restrict__ Wr,
                                                  const float* __restrict__ bl) {
    __shared__ float as_[64 * 64];  // 16 KB
    __shared__ float hs[64 * 64];   // 16 KB
    int tid = threadIdx.x;
    int lane = tid & 63, wave = tid >> 6;
    int rowBase = blockIdx.x * 64;
    float bb = bl[lane];
    float acc[16];
#pragma unroll
    for (int r = 0; r < 16; ++r) acc[r] = bb;

#pragma unroll
    for (int i = 0; i < 4; ++i) {
        int idx = tid + 256 * i;
        int r = idx >> 4;
        int c4 = idx & 15;
        int grow = rowBase + r;
        if (grow >= NN) grow = NN - 1;
        *(float4*)(as_ + r * 64 + c4 * 4) = *(const float4*)(agg + (size_t)grow * HD + c4 * 4);
        *(float4*)(hs + r * 64 + c4 * 4) = *(const float4*)(h + (size_t)grow * HD + c4 * 4);
    }
    __syncthreads();

    for (int k = 0; k < 64; k += 4) {
        float wl0 = Wl[(k + 0) * HD + lane];
        float wl1 = Wl[(k + 1) * HD + lane];
        float wl2 = Wl[(k + 2) * HD + lane];
        float wl3 = Wl[(k + 3) * HD + lane];
        float wr0 = Wr[(k + 0) * HD + lane];
        float wr1 = Wr[(k + 1) * HD + lane];
        float wr2 = Wr[(k + 2) * HD + lane];
        float wr3 = Wr[(k + 3) * HD + lane];
#pragma unroll
        for (int r = 0; r < 16; ++r) {
            float4 av = *(const float4*)(as_ + (wave * 16 + r) * 64 + k);
            float4 hv = *(const float4*)(hs + (wave * 16 + r) * 64 + k);
            acc[r] = fmaf(av.x, wl0, acc[r]);
            acc[r] = fmaf(av.y, wl1, acc[r]);
            acc[r] = fmaf(av.z, wl2, acc[r]);
            acc[r] = fmaf(av.w, wl3, acc[r]);
            acc[r] = fmaf(hv.x, wr0, acc[r]);
            acc[r] = fmaf(hv.y, wr1, acc[r]);
            acc[r] = fmaf(hv.z, wr2, acc[r]);
            acc[r] = fmaf(hv.w, wr3, acc[r]);
        }
    }
#pragma unroll
    for (int r = 0; r < 16; ++r) {
        int row = rowBase + wave * 16 + r;
        if (row < NN) {
            float ho = hs[(wave * 16 + r) * 64 + lane];
            float c = acc[r];
            h[(size_t)row * HD + lane] = ho + (c > 0.f ? c : 0.f);
        }
    }
}

// ---------------- Output GEMM: out = h @ Wout + b_out  [100000,64]x[64,256] ----------------
// 32 rows per block, thread = output column (0..255), LDS-staged h tile.

__global__ __launch_bounds__(256) void gemm_out_k(const float* __restrict__ h, const float* __restrict__ Wout,
                                                  const float* __restrict__ b_out, float* __restrict__ out) {
    __shared__ float hs[32 * 64];  // 8 KB
    int tid = threadIdx.x;
    int rowBase = blockIdx.x * 32;
#pragma unroll
    for (int i = 0; i < 2; ++i) {
        int idx = tid + 256 * i;  // 0..511
        int r = idx >> 4;
        int c4 = idx & 15;
        int grow = rowBase + r;
        if (grow >= NN) grow = NN - 1;
        *(float4*)(hs + r * 64 + c4 * 4) = *(const float4*)(h + (size_t)grow * HD + c4 * 4);
    }
    __syncthreads();

    int j = tid;  // output column
    float bb = b_out[j];
    float acc[32];
#pragma unroll
    for (int r = 0; r < 32; ++r) acc[r] = bb;

    for (int k = 0; k < 64; k += 4) {
        float w0 = Wout[(k + 0) * NC + j];
        float w1 = Wout[(k + 1) * NC + j];
        float w2 = Wout[(k + 2) * NC + j];
        float w3 = Wout[(k + 3) * NC + j];
#pragma unroll
        for (int r = 0; r < 32; ++r) {
            float4 hv = *(const float4*)(hs + r * 64 + k);
            acc[r] = fmaf(hv.x, w0, acc[r]);
            acc[r] = fmaf(hv.y, w1, acc[r]);
            acc[r] = fmaf(hv.z, w2, acc[r]);
            acc[r] = fmaf(hv.w, w3, acc[r]);
        }
    }
#pragma unroll
    for (int r = 0; r < 32; ++r) {
        int row = rowBase + r;
        if (row < NN) out[(size_t)row * NC + j] = acc[r];
    }
}

extern "C" void kernel_launch(void* const* d_in, const int* in_sizes, int n_in,
                              void* d_out, int out_size, void* d_ws, size_t ws_size,
                              hipStream_t stream) {
    const float* x    = (const float*)d_in[0];
    const int*   ei   = (const int*)d_in[1];   // [2, E]: src then dst
    const float* Win  = (const float*)d_in[2];
    const float* b_in = (const float*)d_in[3];
    const float* Wl   = (const float*)d_in[4]; // [4,64,64]
    const float* bl   = (const float*)d_in[5]; // [4,64]
    const float* Wr   = (const float*)d_in[6]; // [4,64,64]
    const float* Wout = (const float*)d_in[7];
    const float* b_out= (const float*)d_in[8];
    float* out = (float*)d_out;

    const int* src = ei;
    const int* dst = ei + EE;

    // workspace layout (16B-aligned chunks)
    char* ws = (char*)d_ws;
    float* h      = (float*)ws;                       // 6.4M floats
    float* agg    = h + (size_t)NN * HD;              // 6.4M floats
    int*   cnt    = (int*)(agg + (size_t)NN * HD);    // 100000
    int*   rowptr = cnt + NN;                         // 100001 (pad to 100004)
    int*   cursor = rowptr + 100004;                  // 100000
    int*   bsum   = cursor + NN;                      // 128
    int*   csr    = bsum + 128;                       // 3.2M
    float* inv    = (float*)(csr + EE);               // 100000

    hipMemsetAsync(cnt, 0, NN * sizeof(int), stream);

    count_deg<<<EE / 256, 256, 0, stream>>>(dst, cnt);
    scan_blocksum<<<NBLK, 256, 0, stream>>>(cnt, bsum);
    scan_offsets<<<1, 128, 0, stream>>>(bsum);
    scan_write<<<NBLK, 256, 0, stream>>>(cnt, bsum, rowptr);
    init_cursor_inv<<<(NN + 255) / 256, 256, 0, stream>>>(rowptr, cnt, cursor, inv);
    fill_csr<<<EE / 256, 256, 0, stream>>>(src, dst, cursor, csr);

    gemm_in<<<(NN + 63) / 64, 256, 0, stream>>>(x, Win, b_in, h);

    for (int i = 0; i < 4; ++i) {
        aggregate<<<NN / 4, 256, 0, stream>>>((const float4*)h, rowptr, csr, inv, (float4*)agg);
        layer_conv<<<(NN + 63) / 64, 256, 0, stream>>>(agg, h, Wl + (size_t)i * HD * HD,
                                                       Wr + (size_t)i * HD * HD, bl + (size_t)i * HD);
    }

    gemm_out_k<<<(NN + 31) / 32, 256, 0, stream>>>(h, Wout, b_out, out);
}